// Round 12
// baseline (5390.730 us; speedup 1.0000x reference)
//
#include <hip/hip_runtime.h>
#include <hip/hip_bf16.h>

// ScalarBorn: 4th-order FD scalar wave + Born scattering with CPML, MI355X.
// R12: barrier-free, LDS-free step kernel. Interleaved (b,s)-pair layout
// (R11) makes every x-neighbor PAIR a 16B-aligned float4 -> direct global
// loads replace the LDS stage; dpsi_x neighbors' psi_x_new recomputed in
// registers (24 threads/block only). Zero __syncthreads -> no vmcnt(0)
// drain; compiler free to pipeline. R9/R11 history: instr cuts saturated;
// barrier serialization is the remaining in-kernel cost.

constexpr int NYX  = 400;
constexpr int NS   = 4;
constexpr int NREC = 100;
constexpr int NT   = 300;
constexpr int PAD  = 22;
constexpr int NP   = 444;
constexpr int NP2  = NP * NP;          // 197136
constexpr int SNP2 = NS * NP2;         // 788544
constexpr float DT    = 0.0005f;
constexpr float INVH  = 0.2f;
constexpr float INVH2 = 0.04f;
constexpr float C1A = 1.0f / 12.0f;
constexpr float C1B = 2.0f / 3.0f;
constexpr float C2A = -1.0f / 12.0f;
constexpr float C2B = 4.0f / 3.0f;
constexpr float C2C = -2.5f;

// interleaved state: (b,s) pair for grid index idx lives at [2*idx, 2*idx+1]
__device__ __align__(16) float g_w[2][2 * SNP2];   // wavefield ping-pong
__device__ __align__(16) float g_px[2][2 * SNP2];  // psi_x dbuf
__device__ __align__(16) float g_py[2][2 * SNP2];  // psi_y dbuf
__device__ __align__(16) float g_zx[2 * SNP2];     // zeta_x
__device__ __align__(16) float g_zy[2 * SNP2];     // zeta_y
__device__ __align__(16) float g_vb[2 * NP2];      // (v2dt2, bscale) pairs
__device__ float g_pa[NP];
__device__ float g_pb[NP];
__device__ float g_fbg[NT * NS];
__device__ float g_fsc[NT * NS];
__device__ int   g_spos[2 * NS];
__device__ int   g_mode;               // 1 = bf16 io, 0 = f32 io

__device__ __forceinline__ int clampi(int v, int lo, int hi) {
    return v < lo ? lo : (v > hi ? hi : v);
}
__device__ __forceinline__ float in_ld(const void* p, int i) {
    if (g_mode) return __bfloat162float(((const __hip_bfloat16*)p)[i]);
    return ((const float*)p)[i];
}
__device__ __forceinline__ void out_st(void* p, int i, float v) {
    if (g_mode) ((__hip_bfloat16*)p)[i] = __float2bfloat16(v);
    else        ((float*)p)[i] = v;
}
// float4 = (b0,s0,b1,s1) at row yy, pair column j of shot s; 0 if row OOB
__device__ __forceinline__ float4 ld4(const float* w, int s, int yy, int j) {
    if ((unsigned)yy >= (unsigned)NP) return make_float4(0.f, 0.f, 0.f, 0.f);
    return *(const float4*)(w + 2 * (s * NP2 + yy * NP + 2 * j));
}

__global__ void detect_mode(const void* vptr) {
    if (threadIdx.x == 0 && blockIdx.x == 0) {
        const __hip_bfloat16* p = (const __hip_bfloat16*)vptr;
        int ok = 1;
        for (int i = 0; i < 32; i += 2) {
            float f = __bfloat162float(p[i]);
            if (!(f >= 1000.f && f <= 3000.f)) ok = 0;
        }
        g_mode = ok;
    }
}

__global__ void zero_state() {
    int i = blockIdx.x * blockDim.x + threadIdx.x;
    if (i >= SNP2 / 2) return;           // each array = 2*SNP2 floats
    float4 z = make_float4(0.f, 0.f, 0.f, 0.f);
    ((float4*)g_w[0])[i] = z;  ((float4*)g_w[1])[i] = z;
    ((float4*)g_px[0])[i] = z; ((float4*)g_px[1])[i] = z;
    ((float4*)g_py[0])[i] = z; ((float4*)g_py[1])[i] = z;
    ((float4*)g_zx)[i] = z;    ((float4*)g_zy)[i] = z;
}

__global__ void prep_pad(const void* __restrict__ v, const void* __restrict__ sc) {
    int i = blockIdx.x * blockDim.x + threadIdx.x;
    if (i >= NP2) return;
    int y = i / NP, x = i % NP;
    int vy = clampi(y - PAD, 0, NYX - 1);
    int vx = clampi(x - PAD, 0, NYX - 1);
    float vv = in_ld(v, vy * NYX + vx);
    float vd = vv * DT;
    float s = 0.f;
    if (y >= PAD && y < PAD + NYX && x >= PAD && x < PAD + NYX)
        s = in_ld(sc, (y - PAD) * NYX + (x - PAD));
    g_vb[2 * i]     = vd * vd;
    g_vb[2 * i + 1] = 2.f * vv * s * DT * DT;
    if (i < NP) {
        float fi = (float)i;
        float f1 = fminf(fmaxf((22.f - fi) * 0.05f, 0.f), 1.f);
        float f2 = fminf(fmaxf((fi - 421.f) * 0.05f, 0.f), 1.f);
        float frac = fmaxf(f1, f2);
        float sigma = 259.0408229f * frac * frac;
        const float alpha = 78.53981634f;
        float a = expf(-(sigma + alpha) * DT);
        g_pa[i] = a;
        g_pb[i] = (sigma > 0.f) ? sigma / (sigma + alpha) * (a - 1.f) : 0.f;
    }
}

__global__ void prep_src(const void* __restrict__ amp, const int* __restrict__ sloc,
                         const void* __restrict__ v, const void* __restrict__ sc) {
    int i = blockIdx.x * blockDim.x + threadIdx.x;
    if (i >= NT * NS) return;
    int s = i % NS, t = i / NS;
    int ly = clampi(sloc[s * 2 + 0], 0, NYX - 1);
    int lx = clampi(sloc[s * 2 + 1], 0, NYX - 1);
    float a  = in_ld(amp, s * NT + t);
    float vv = in_ld(v,  ly * NYX + lx);
    float ss = in_ld(sc, ly * NYX + lx);
    g_fbg[i] = -a * vv * vv * DT * DT;
    g_fsc[i] = -2.f * a * vv * ss * DT * DT;
    if (i < NS) {
        g_spos[2 * i]     = ly + PAD;
        g_spos[2 * i + 1] = lx + PAD;
    }
}

// one fused timestep, no barriers. Block = row y of shot s; 256 thr x 2 pts.
__global__ void __launch_bounds__(256)
step_fused(int t, const int* __restrict__ rloc, const int* __restrict__ rbloc,
           void* __restrict__ out) {
    const int i = threadIdx.x;
    const int y = blockIdx.y;
    const int s = blockIdx.z;
    const int cur = t & 1, nxt = cur ^ 1;

    if (t > 0 && y == 0 && i < 2 * NREC) {    // record step t-1
        int r = i % NREC;
        bool isbg = i < NREC;
        const int* rl = isbg ? rbloc : rloc;
        int ry = clampi(rl[(s * NREC + r) * 2 + 0], 0, NYX - 1) + PAD;
        int rx = clampi(rl[(s * NREC + r) * 2 + 1], 0, NYX - 1) + PAD;
        float val = g_w[cur][2 * (s * NP2 + ry * NP + rx) + (isbg ? 0 : 1)];
        int base = isbg ? (2 * SNP2) : (2 * SNP2 + NS * NREC * NT);
        out_st(out, base + (s * NREC + r) * NT + (t - 1), val);
    }
    if (i >= 222) return;

    const int x0 = 2 * i, x1 = x0 + 1;
    const int yx  = y * NP + x0;
    const int idx = s * NP2 + yx;
    const float* wc = g_w[cur];
    const float4 z4 = make_float4(0.f, 0.f, 0.f, 0.f);

    // own + x-neighbor pairs (all 16B-aligned float4)
    float4 w4 = *(const float4*)(wc + 2 * idx);
    float4 tm = (i >= 1)   ? *(const float4*)(wc + 2 * (idx - 2)) : z4;
    float4 tp = (i <= 220) ? *(const float4*)(wc + 2 * (idx + 2)) : z4;

    float d2x_b0 = (C2A * (tm.x + tp.x) + C2B * (tm.z + w4.z) + C2C * w4.x) * INVH2;
    float d2x_s0 = (C2A * (tm.y + tp.y) + C2B * (tm.w + w4.w) + C2C * w4.y) * INVH2;
    float d2x_b1 = (C2A * (tm.z + tp.z) + C2B * (w4.x + tp.x) + C2C * w4.z) * INVH2;
    float d2x_s1 = (C2A * (tm.w + tp.w) + C2B * (w4.y + tp.y) + C2C * w4.w) * INVH2;

    const float pbx0 = g_pb[x0], pbx1 = g_pb[x1];
    const float pax0 = g_pa[x0], pax1 = g_pa[x1];
    const bool pxreg = (i <= 11 || i >= 210);

    // own psi_x update (pb pair-uniform: frame col pairs fully in/out)
    float4 pxn = z4;
    if (pxreg && pbx0 != 0.f) {
        float4 pxo = *(const float4*)(g_px[cur] + 2 * idx);
        float dwb0 = (C1A * tm.x - C1B * tm.z + C1B * w4.z - C1A * tp.x) * INVH;
        float dws0 = (C1A * tm.y - C1B * tm.w + C1B * w4.w - C1A * tp.y) * INVH;
        float dwb1 = (C1A * tm.z - C1B * w4.x + C1B * tp.x - C1A * tp.z) * INVH;
        float dws1 = (C1A * tm.w - C1B * w4.y + C1B * tp.y - C1A * tp.w) * INVH;
        pxn.x = pax0 * pxo.x + pbx0 * dwb0;
        pxn.y = pax0 * pxo.y + pbx0 * dws0;
        pxn.z = pax1 * pxo.z + pbx1 * dwb1;
        pxn.w = pax1 * pxo.w + pbx1 * dws1;
        *(float4*)(g_px[nxt] + 2 * idx) = pxn;
    }

    // dpsi_x: recompute neighbor pairs' psi_x_new in registers (no barrier)
    float dpx_b0 = 0.f, dpx_b1 = 0.f, dpx_s0 = 0.f, dpx_s1 = 0.f;
    if (pxreg) {
        float4 tmm = (i >= 2)   ? *(const float4*)(wc + 2 * (idx - 4)) : z4;
        float4 tpp = (i <= 219) ? *(const float4*)(wc + 2 * (idx + 4)) : z4;
        float4 nm = z4, np = z4;
        if (i >= 1 && g_pb[x0 - 2] != 0.f) {       // pair i-1 (cols x0-2,x0-1)
            float4 pxom = *(const float4*)(g_px[cur] + 2 * (idx - 2));
            float pbm0 = g_pb[x0 - 2], pbm1 = g_pb[x0 - 1];
            float pam0 = g_pa[x0 - 2], pam1 = g_pa[x0 - 1];
            float db0 = (C1A * tmm.x - C1B * tmm.z + C1B * tm.z - C1A * w4.x) * INVH;
            float ds0 = (C1A * tmm.y - C1B * tmm.w + C1B * tm.w - C1A * w4.y) * INVH;
            float db1 = (C1A * tmm.z - C1B * tm.x + C1B * w4.x - C1A * w4.z) * INVH;
            float ds1 = (C1A * tmm.w - C1B * tm.y + C1B * w4.y - C1A * w4.w) * INVH;
            nm.x = pam0 * pxom.x + pbm0 * db0;
            nm.y = pam0 * pxom.y + pbm0 * ds0;
            nm.z = pam1 * pxom.z + pbm1 * db1;
            nm.w = pam1 * pxom.w + pbm1 * ds1;
        }
        if (i <= 220 && g_pb[x0 + 2] != 0.f) {     // pair i+1 (cols x0+2,x0+3)
            float4 pxop = *(const float4*)(g_px[cur] + 2 * (idx + 2));
            float pbp0 = g_pb[x0 + 2], pbp1 = g_pb[x0 + 3];
            float pap0 = g_pa[x0 + 2], pap1 = g_pa[x0 + 3];
            float db0 = (C1A * w4.x - C1B * w4.z + C1B * tp.z - C1A * tpp.x) * INVH;
            float ds0 = (C1A * w4.y - C1B * w4.w + C1B * tp.w - C1A * tpp.y) * INVH;
            float db1 = (C1A * w4.z - C1B * tp.x + C1B * tpp.x - C1A * tpp.z) * INVH;
            float ds1 = (C1A * w4.w - C1B * tp.y + C1B * tpp.y - C1A * tpp.w) * INVH;
            np.x = pap0 * pxop.x + pbp0 * db0;
            np.y = pap0 * pxop.y + pbp0 * ds0;
            np.z = pap1 * pxop.z + pbp1 * db1;
            np.w = pap1 * pxop.w + pbp1 * ds1;
        }
        dpx_b0 = (C1A * nm.x - C1B * nm.z + C1B * pxn.z - C1A * np.x) * INVH;
        dpx_s0 = (C1A * nm.y - C1B * nm.w + C1B * pxn.w - C1A * np.y) * INVH;
        dpx_b1 = (C1A * nm.z - C1B * pxn.x + C1B * np.x - C1A * np.z) * INVH;
        dpx_s1 = (C1A * nm.w - C1B * pxn.y + C1B * np.y - C1A * np.w) * INVH;
    }

    // ---- y direction ----
    const float pby = g_pb[y];               // block-uniform
    const bool yframe = (y <= 23 || y >= 420);
    float d2y_b0, d2y_b1, d2y_s0, d2y_s1;
    float dpy_b0 = 0.f, dpy_b1 = 0.f, dpy_s0 = 0.f, dpy_s1 = 0.f;
    if (yframe) {
        float4 wy[9];                        // rows y-4..y+4
        #pragma unroll
        for (int k = 0; k < 9; ++k)
            wy[k] = (k == 4) ? w4 : ld4(wc, s, y - 4 + k, i);
        d2y_b0 = (C2A * (wy[2].x + wy[6].x) + C2B * (wy[3].x + wy[5].x) + C2C * wy[4].x) * INVH2;
        d2y_s0 = (C2A * (wy[2].y + wy[6].y) + C2B * (wy[3].y + wy[5].y) + C2C * wy[4].y) * INVH2;
        d2y_b1 = (C2A * (wy[2].z + wy[6].z) + C2B * (wy[3].z + wy[5].z) + C2C * wy[4].z) * INVH2;
        d2y_s1 = (C2A * (wy[2].w + wy[6].w) + C2B * (wy[3].w + wy[5].w) + C2C * wy[4].w) * INVH2;
        float4 pn[5];                        // psi_y_new rows y-2..y+2
        #pragma unroll
        for (int k = 0; k < 5; ++k) {
            int yy = y - 2 + k;
            float pbv = ((unsigned)yy < (unsigned)NP) ? g_pb[yy] : 0.f;  // uniform
            float4 r = z4;
            if (pbv != 0.f) {
                float pav = g_pa[yy];
                float4 po = *(const float4*)(g_py[cur] + 2 * (s * NP2 + yy * NP + x0));
                float db0 = (C1A * wy[k].x - C1B * wy[k+1].x + C1B * wy[k+3].x - C1A * wy[k+4].x) * INVH;
                float ds0 = (C1A * wy[k].y - C1B * wy[k+1].y + C1B * wy[k+3].y - C1A * wy[k+4].y) * INVH;
                float db1 = (C1A * wy[k].z - C1B * wy[k+1].z + C1B * wy[k+3].z - C1A * wy[k+4].z) * INVH;
                float ds1 = (C1A * wy[k].w - C1B * wy[k+1].w + C1B * wy[k+3].w - C1A * wy[k+4].w) * INVH;
                r.x = pav * po.x + pbv * db0;  r.y = pav * po.y + pbv * ds0;
                r.z = pav * po.z + pbv * db1;  r.w = pav * po.w + pbv * ds1;
            }
            pn[k] = r;
        }
        dpy_b0 = (C1A * pn[0].x - C1B * pn[1].x + C1B * pn[3].x - C1A * pn[4].x) * INVH;
        dpy_s0 = (C1A * pn[0].y - C1B * pn[1].y + C1B * pn[3].y - C1A * pn[4].y) * INVH;
        dpy_b1 = (C1A * pn[0].z - C1B * pn[1].z + C1B * pn[3].z - C1A * pn[4].z) * INVH;
        dpy_s1 = (C1A * pn[0].w - C1B * pn[1].w + C1B * pn[3].w - C1A * pn[4].w) * INVH;
        if (pby != 0.f)
            *(float4*)(g_py[nxt] + 2 * idx) = pn[2];
    } else {                                 // interior: 4 float4 row loads
        float4 m2 = *(const float4*)(wc + 2 * (idx - 2 * NP));
        float4 m1 = *(const float4*)(wc + 2 * (idx - NP));
        float4 p1 = *(const float4*)(wc + 2 * (idx + NP));
        float4 p2 = *(const float4*)(wc + 2 * (idx + 2 * NP));
        d2y_b0 = (C2A * (m2.x + p2.x) + C2B * (m1.x + p1.x) + C2C * w4.x) * INVH2;
        d2y_s0 = (C2A * (m2.y + p2.y) + C2B * (m1.y + p1.y) + C2C * w4.y) * INVH2;
        d2y_b1 = (C2A * (m2.z + p2.z) + C2B * (m1.z + p1.z) + C2C * w4.z) * INVH2;
        d2y_s1 = (C2A * (m2.w + p2.w) + C2B * (m1.w + p1.w) + C2C * w4.w) * INVH2;
    }

    // ---- zeta (in-place, own points) ----
    float zy_b0 = 0.f, zy_b1 = 0.f, zy_s0 = 0.f, zy_s1 = 0.f;
    float zx_b0 = 0.f, zx_b1 = 0.f, zx_s0 = 0.f, zx_s1 = 0.f;
    if (pby != 0.f) {
        float pay = g_pa[y];
        float4 zo = *(const float4*)(g_zy + 2 * idx);
        zy_b0 = pay * zo.x + pby * (d2y_b0 + dpy_b0);
        zy_s0 = pay * zo.y + pby * (d2y_s0 + dpy_s0);
        zy_b1 = pay * zo.z + pby * (d2y_b1 + dpy_b1);
        zy_s1 = pay * zo.w + pby * (d2y_s1 + dpy_s1);
        *(float4*)(g_zy + 2 * idx) = make_float4(zy_b0, zy_s0, zy_b1, zy_s1);
    }
    if (pbx0 != 0.f) {                       // pair-uniform
        float4 zo = *(const float4*)(g_zx + 2 * idx);
        zx_b0 = pax0 * zo.x + pbx0 * (d2x_b0 + dpx_b0);
        zx_s0 = pax0 * zo.y + pbx0 * (d2x_s0 + dpx_s0);
        zx_b1 = pax1 * zo.z + pbx1 * (d2x_b1 + dpx_b1);
        zx_s1 = pax1 * zo.w + pbx1 * (d2x_s1 + dpx_s1);
        *(float4*)(g_zx + 2 * idx) = make_float4(zx_b0, zx_s0, zx_b1, zx_s1);
    }

    // ---- lap + leapfrog + Born + source ----
    float4 vb   = *(const float4*)(g_vb + 2 * yx);        // (v0,bs0,v1,bs1)
    float4 prev = *(const float4*)(g_w[nxt] + 2 * idx);
    float lap_b0 = d2y_b0 + d2x_b0 + dpy_b0 + dpx_b0 + zy_b0 + zx_b0;
    float lap_s0 = d2y_s0 + d2x_s0 + dpy_s0 + dpx_s0 + zy_s0 + zx_s0;
    float lap_b1 = d2y_b1 + d2x_b1 + dpy_b1 + dpx_b1 + zy_b1 + zx_b1;
    float lap_s1 = d2y_s1 + d2x_s1 + dpy_s1 + dpx_s1 + zy_s1 + zx_s1;
    float wn_b0 = vb.x * lap_b0 + 2.f * w4.x - prev.x;
    float wn_s0 = vb.x * lap_s0 + 2.f * w4.y - prev.y + vb.y * lap_b0;
    float wn_b1 = vb.z * lap_b1 + 2.f * w4.z - prev.z;
    float wn_s1 = vb.z * lap_s1 + 2.f * w4.w - prev.w + vb.w * lap_b1;
    if (y == g_spos[2 * s]) {
        int sx = g_spos[2 * s + 1];
        if (sx == x0)      { wn_b0 += g_fbg[t * NS + s]; wn_s0 += g_fsc[t * NS + s]; }
        else if (sx == x1) { wn_b1 += g_fbg[t * NS + s]; wn_s1 += g_fsc[t * NS + s]; }
    }
    *(float4*)(g_w[nxt] + 2 * idx) = make_float4(wn_b0, wn_s0, wn_b1, wn_s1);
}

__global__ void finalize(const int* __restrict__ rloc, const int* __restrict__ rbloc,
                         void* __restrict__ out) {
    int i = blockIdx.x * blockDim.x + threadIdx.x;
    const float* w0 = g_w[0];     // NT even: newest field in buffer 0
    if (i < SNP2) {
        out_st(out, i,        w0[2 * i]);       // bg flat
        out_st(out, SNP2 + i, w0[2 * i + 1]);   // scattered flat
    }
    if (i < 2 * NS * NREC) {      // record last step (t = NT-1)
        bool isbg = i < NS * NREC;
        int k = isbg ? i : i - NS * NREC;
        int s = k / NREC, r = k % NREC;
        const int* rl = isbg ? rbloc : rloc;
        int ry = clampi(rl[(s * NREC + r) * 2 + 0], 0, NYX - 1) + PAD;
        int rx = clampi(rl[(s * NREC + r) * 2 + 1], 0, NYX - 1) + PAD;
        float val = w0[2 * (s * NP2 + ry * NP + rx) + (isbg ? 0 : 1)];
        int base = isbg ? (2 * SNP2) : (2 * SNP2 + NS * NREC * NT);
        out_st(out, base + (s * NREC + r) * NT + (NT - 1), val);
    }
}

extern "C" void kernel_launch(void* const* d_in, const int* in_sizes, int n_in,
                              void* d_out, int out_size, void* d_ws, size_t ws_size,
                              hipStream_t stream) {
    const void* v   = d_in[0];
    const void* sc  = d_in[1];
    const void* amp = d_in[2];
    const int* sloc  = (const int*)d_in[3];
    const int* rloc  = (const int*)d_in[4];
    const int* rbloc = (const int*)d_in[5];

    detect_mode<<<1, 64, 0, stream>>>(v);
    zero_state<<<(SNP2 / 2 + 255) / 256, 256, 0, stream>>>();
    prep_pad<<<(NP2 + 255) / 256, 256, 0, stream>>>(v, sc);
    prep_src<<<(NT * NS + 255) / 256, 256, 0, stream>>>(amp, sloc, v, sc);

    dim3 grid(1, NP, NS);
    for (int t = 0; t < NT; ++t)
        step_fused<<<grid, 256, 0, stream>>>(t, rloc, rbloc, d_out);

    finalize<<<(SNP2 + 255) / 256, 256, 0, stream>>>(rloc, rbloc, d_out);
}

// Round 13
// 4546.101 us; speedup vs baseline: 1.1858x; 1.1858x over previous
//
#include <hip/hip_runtime.h>
#include <hip/hip_bf16.h>

// ScalarBorn: 4th-order FD scalar wave + Born scattering with CPML, MI355X.
// R13: R11 (best, 3829us) with the SECOND barrier removed surgically:
// w stays staged in LDS (R12 proved replacing LDS with overlapping global
// loads regresses 1.4x), but dpsi_x neighbors' psi_x_new are recomputed
// in-register from LDS w taps + 2 extra psi_x_old pair loads — only on the
// 24 pxreg threads/block. One barrier total; spx LDS array deleted.

constexpr int NYX  = 400;
constexpr int NS   = 4;
constexpr int NREC = 100;
constexpr int NT   = 300;
constexpr int PAD  = 22;
constexpr int NP   = 444;
constexpr int NP2  = NP * NP;          // 197136
constexpr int SNP2 = NS * NP2;         // 788544
constexpr float DT    = 0.0005f;
constexpr float INVH  = 0.2f;
constexpr float INVH2 = 0.04f;
constexpr float C1A = 1.0f / 12.0f;
constexpr float C1B = 2.0f / 3.0f;
constexpr float C2A = -1.0f / 12.0f;
constexpr float C2B = 4.0f / 3.0f;
constexpr float C2C = -2.5f;

// interleaved state: (b,s) pair for grid index idx lives at [2*idx, 2*idx+1]
__device__ __align__(16) float g_w[2][2 * SNP2];   // wavefield ping-pong
__device__ __align__(16) float g_px[2][2 * SNP2];  // psi_x dbuf
__device__ __align__(16) float g_py[2][2 * SNP2];  // psi_y dbuf
__device__ __align__(16) float g_zx[2 * SNP2];     // zeta_x
__device__ __align__(16) float g_zy[2 * SNP2];     // zeta_y
__device__ __align__(16) float g_vb[2 * NP2];      // (v2dt2, bscale) pairs
__device__ float g_pa[NP];
__device__ float g_pb[NP];
__device__ float g_fbg[NT * NS];
__device__ float g_fsc[NT * NS];
__device__ int   g_spos[2 * NS];
__device__ int   g_mode;               // 1 = bf16 io, 0 = f32 io

__device__ __forceinline__ int clampi(int v, int lo, int hi) {
    return v < lo ? lo : (v > hi ? hi : v);
}
__device__ __forceinline__ float in_ld(const void* p, int i) {
    if (g_mode) return __bfloat162float(((const __hip_bfloat16*)p)[i]);
    return ((const float*)p)[i];
}
__device__ __forceinline__ void out_st(void* p, int i, float v) {
    if (g_mode) ((__hip_bfloat16*)p)[i] = __float2bfloat16(v);
    else        ((float*)p)[i] = v;
}
// float4 = (b0,s0,b1,s1) at row yy, pair column j of shot s; 0 if row OOB
__device__ __forceinline__ float4 ld4(const float* w, int s, int yy, int j) {
    if ((unsigned)yy >= (unsigned)NP) return make_float4(0.f, 0.f, 0.f, 0.f);
    return *(const float4*)(w + 2 * (s * NP2 + yy * NP + 2 * j));
}

__global__ void detect_mode(const void* vptr) {
    if (threadIdx.x == 0 && blockIdx.x == 0) {
        const __hip_bfloat16* p = (const __hip_bfloat16*)vptr;
        int ok = 1;
        for (int i = 0; i < 32; i += 2) {
            float f = __bfloat162float(p[i]);
            if (!(f >= 1000.f && f <= 3000.f)) ok = 0;
        }
        g_mode = ok;
    }
}

__global__ void zero_state() {
    int i = blockIdx.x * blockDim.x + threadIdx.x;
    if (i >= SNP2 / 2) return;           // each array = 2*SNP2 floats
    float4 z = make_float4(0.f, 0.f, 0.f, 0.f);
    ((float4*)g_w[0])[i] = z;  ((float4*)g_w[1])[i] = z;
    ((float4*)g_px[0])[i] = z; ((float4*)g_px[1])[i] = z;
    ((float4*)g_py[0])[i] = z; ((float4*)g_py[1])[i] = z;
    ((float4*)g_zx)[i] = z;    ((float4*)g_zy)[i] = z;
}

__global__ void prep_pad(const void* __restrict__ v, const void* __restrict__ sc) {
    int i = blockIdx.x * blockDim.x + threadIdx.x;
    if (i >= NP2) return;
    int y = i / NP, x = i % NP;
    int vy = clampi(y - PAD, 0, NYX - 1);
    int vx = clampi(x - PAD, 0, NYX - 1);
    float vv = in_ld(v, vy * NYX + vx);
    float vd = vv * DT;
    float s = 0.f;
    if (y >= PAD && y < PAD + NYX && x >= PAD && x < PAD + NYX)
        s = in_ld(sc, (y - PAD) * NYX + (x - PAD));
    g_vb[2 * i]     = vd * vd;
    g_vb[2 * i + 1] = 2.f * vv * s * DT * DT;
    if (i < NP) {
        float fi = (float)i;
        float f1 = fminf(fmaxf((22.f - fi) * 0.05f, 0.f), 1.f);
        float f2 = fminf(fmaxf((fi - 421.f) * 0.05f, 0.f), 1.f);
        float frac = fmaxf(f1, f2);
        float sigma = 259.0408229f * frac * frac;
        const float alpha = 78.53981634f;
        float a = expf(-(sigma + alpha) * DT);
        g_pa[i] = a;
        g_pb[i] = (sigma > 0.f) ? sigma / (sigma + alpha) * (a - 1.f) : 0.f;
    }
}

__global__ void prep_src(const void* __restrict__ amp, const int* __restrict__ sloc,
                         const void* __restrict__ v, const void* __restrict__ sc) {
    int i = blockIdx.x * blockDim.x + threadIdx.x;
    if (i >= NT * NS) return;
    int s = i % NS, t = i / NS;
    int ly = clampi(sloc[s * 2 + 0], 0, NYX - 1);
    int lx = clampi(sloc[s * 2 + 1], 0, NYX - 1);
    float a  = in_ld(amp, s * NT + t);
    float vv = in_ld(v,  ly * NYX + lx);
    float ss = in_ld(sc, ly * NYX + lx);
    g_fbg[i] = -a * vv * vv * DT * DT;
    g_fsc[i] = -2.f * a * vv * ss * DT * DT;
    if (i < NS) {
        g_spos[2 * i]     = ly + PAD;
        g_spos[2 * i + 1] = lx + PAD;
    }
}

// one fused timestep, ONE barrier. Block = row y of shot s; 256 thr x 2 pts.
// LDS: (b,s) pair of logical col c at float index 2*(c+2); pads zeroed.
__global__ void __launch_bounds__(256)
step_fused(int t, const int* __restrict__ rloc, const int* __restrict__ rbloc,
           void* __restrict__ out) {
    const int i = threadIdx.x;
    const int y = blockIdx.y;
    const int s = blockIdx.z;
    const int cur = t & 1, nxt = cur ^ 1;
    __shared__ __align__(16) float sw[904];

    if (t > 0 && y == 0 && i < 2 * NREC) {    // record step t-1
        int r = i % NREC;
        bool isbg = i < NREC;
        const int* rl = isbg ? rbloc : rloc;
        int ry = clampi(rl[(s * NREC + r) * 2 + 0], 0, NYX - 1) + PAD;
        int rx = clampi(rl[(s * NREC + r) * 2 + 1], 0, NYX - 1) + PAD;
        float val = g_w[cur][2 * (s * NP2 + ry * NP + rx) + (isbg ? 0 : 1)];
        int base = isbg ? (2 * SNP2) : (2 * SNP2 + NS * NREC * NT);
        out_st(out, base + (s * NREC + r) * NT + (t - 1), val);
    }

    const bool active = i < 222;
    const int x0 = 2 * i, x1 = x0 + 1;
    const int yx  = y * NP + x0;
    const int idx = s * NP2 + yx;
    const float* wc = g_w[cur];
    const float4 z4 = make_float4(0.f, 0.f, 0.f, 0.f);

    float4 w4 = z4;                          // (b0,s0,b1,s1)
    if (active) {
        w4 = *(const float4*)(wc + 2 * idx);
        *(float4*)&sw[4 * i + 4] = w4;
    } else if (i == 222) {
        #pragma unroll
        for (int k = 0; k < 4; ++k) sw[k] = 0.f;
    } else if (i == 223) {
        #pragma unroll
        for (int k = 892; k < 904; ++k) sw[k] = 0.f;
    }
    __syncthreads();
    if (!active) return;

    // ---- x stencils from LDS ----
    float4 ldm = *(const float4*)&sw[4 * i];       // pair i-1 (cols x0-2,x0-1)
    float4 ldp = *(const float4*)&sw[4 * i + 8];   // pair i+1 (cols x0+2,x0+3)
    float d2x_b0 = (C2A * (ldm.x + ldp.x) + C2B * (ldm.z + w4.z) + C2C * w4.x) * INVH2;
    float d2x_s0 = (C2A * (ldm.y + ldp.y) + C2B * (ldm.w + w4.w) + C2C * w4.y) * INVH2;
    float d2x_b1 = (C2A * (ldm.z + ldp.z) + C2B * (w4.x + ldp.x) + C2C * w4.z) * INVH2;
    float d2x_s1 = (C2A * (ldm.w + ldp.w) + C2B * (w4.y + ldp.y) + C2C * w4.w) * INVH2;

    const float pbx0 = g_pb[x0], pbx1 = g_pb[x1];
    const float pax0 = g_pa[x0], pax1 = g_pa[x1];
    const bool pxreg = (i <= 11 || i >= 210);

    // own psi_x update (pb pair-uniform: frame col pairs fully in/out)
    float4 pxn = z4;
    if (pxreg && pbx0 != 0.f) {
        float4 pxo = *(const float4*)(g_px[cur] + 2 * idx);
        float dwb0 = (C1A * ldm.x - C1B * ldm.z + C1B * w4.z - C1A * ldp.x) * INVH;
        float dws0 = (C1A * ldm.y - C1B * ldm.w + C1B * w4.w - C1A * ldp.y) * INVH;
        float dwb1 = (C1A * ldm.z - C1B * w4.x + C1B * ldp.x - C1A * ldp.z) * INVH;
        float dws1 = (C1A * ldm.w - C1B * w4.y + C1B * ldp.y - C1A * ldp.w) * INVH;
        pxn.x = pax0 * pxo.x + pbx0 * dwb0;
        pxn.y = pax0 * pxo.y + pbx0 * dws0;
        pxn.z = pax1 * pxo.z + pbx1 * dwb1;
        pxn.w = pax1 * pxo.w + pbx1 * dws1;
        *(float4*)(g_px[nxt] + 2 * idx) = pxn;
    }

    // dpsi_x: recompute neighbor pairs' psi_x_new from LDS w (no 2nd barrier)
    float dpx_b0 = 0.f, dpx_b1 = 0.f, dpx_s0 = 0.f, dpx_s1 = 0.f;
    if (pxreg) {
        float4 tmm = (i >= 2)   ? *(const float4*)&sw[4 * i - 4]  : z4;  // pair i-2
        float4 tpp = (i <= 219) ? *(const float4*)&sw[4 * i + 12] : z4;  // pair i+2
        float4 nm = z4, np = z4;
        if (i >= 1 && g_pb[x0 - 2] != 0.f) {       // pair i-1 (cols x0-2,x0-1)
            float4 pxom = *(const float4*)(g_px[cur] + 2 * (idx - 2));
            float pbm0 = g_pb[x0 - 2], pbm1 = g_pb[x0 - 1];
            float pam0 = g_pa[x0 - 2], pam1 = g_pa[x0 - 1];
            float db0 = (C1A * tmm.x - C1B * tmm.z + C1B * ldm.z - C1A * w4.x) * INVH;
            float ds0 = (C1A * tmm.y - C1B * tmm.w + C1B * ldm.w - C1A * w4.y) * INVH;
            float db1 = (C1A * tmm.z - C1B * ldm.x + C1B * w4.x - C1A * w4.z) * INVH;
            float ds1 = (C1A * tmm.w - C1B * ldm.y + C1B * w4.y - C1A * w4.w) * INVH;
            nm.x = pam0 * pxom.x + pbm0 * db0;
            nm.y = pam0 * pxom.y + pbm0 * ds0;
            nm.z = pam1 * pxom.z + pbm1 * db1;
            nm.w = pam1 * pxom.w + pbm1 * ds1;
        }
        if (i <= 220 && g_pb[x0 + 2] != 0.f) {     // pair i+1 (cols x0+2,x0+3)
            float4 pxop = *(const float4*)(g_px[cur] + 2 * (idx + 2));
            float pbp0 = g_pb[x0 + 2], pbp1 = g_pb[x0 + 3];
            float pap0 = g_pa[x0 + 2], pap1 = g_pa[x0 + 3];
            float db0 = (C1A * w4.x - C1B * w4.z + C1B * ldp.z - C1A * tpp.x) * INVH;
            float ds0 = (C1A * w4.y - C1B * w4.w + C1B * ldp.w - C1A * tpp.y) * INVH;
            float db1 = (C1A * w4.z - C1B * ldp.x + C1B * tpp.x - C1A * tpp.z) * INVH;
            float ds1 = (C1A * w4.w - C1B * ldp.y + C1B * tpp.y - C1A * tpp.w) * INVH;
            np.x = pap0 * pxop.x + pbp0 * db0;
            np.y = pap0 * pxop.y + pbp0 * ds0;
            np.z = pap1 * pxop.z + pbp1 * db1;
            np.w = pap1 * pxop.w + pbp1 * ds1;
        }
        dpx_b0 = (C1A * nm.x - C1B * nm.z + C1B * pxn.z - C1A * np.x) * INVH;
        dpx_s0 = (C1A * nm.y - C1B * nm.w + C1B * pxn.w - C1A * np.y) * INVH;
        dpx_b1 = (C1A * nm.z - C1B * pxn.x + C1B * np.x - C1A * np.z) * INVH;
        dpx_s1 = (C1A * nm.w - C1B * pxn.y + C1B * np.y - C1A * np.w) * INVH;
    }

    // ---- y direction ----
    const float pby = g_pb[y];               // block-uniform
    const bool yframe = (y <= 23 || y >= 420);
    float d2y_b0, d2y_b1, d2y_s0, d2y_s1;
    float dpy_b0 = 0.f, dpy_b1 = 0.f, dpy_s0 = 0.f, dpy_s1 = 0.f;
    if (yframe) {
        float4 wy[9];                        // rows y-4..y+4
        #pragma unroll
        for (int k = 0; k < 9; ++k)
            wy[k] = (k == 4) ? w4 : ld4(wc, s, y - 4 + k, i);
        d2y_b0 = (C2A * (wy[2].x + wy[6].x) + C2B * (wy[3].x + wy[5].x) + C2C * wy[4].x) * INVH2;
        d2y_s0 = (C2A * (wy[2].y + wy[6].y) + C2B * (wy[3].y + wy[5].y) + C2C * wy[4].y) * INVH2;
        d2y_b1 = (C2A * (wy[2].z + wy[6].z) + C2B * (wy[3].z + wy[5].z) + C2C * wy[4].z) * INVH2;
        d2y_s1 = (C2A * (wy[2].w + wy[6].w) + C2B * (wy[3].w + wy[5].w) + C2C * wy[4].w) * INVH2;
        float4 pn[5];                        // psi_y_new rows y-2..y+2
        #pragma unroll
        for (int k = 0; k < 5; ++k) {
            int yy = y - 2 + k;
            float pbv = ((unsigned)yy < (unsigned)NP) ? g_pb[yy] : 0.f;  // uniform
            float4 r = z4;
            if (pbv != 0.f) {
                float pav = g_pa[yy];
                float4 po = *(const float4*)(g_py[cur] + 2 * (s * NP2 + yy * NP + x0));
                float db0 = (C1A * wy[k].x - C1B * wy[k+1].x + C1B * wy[k+3].x - C1A * wy[k+4].x) * INVH;
                float ds0 = (C1A * wy[k].y - C1B * wy[k+1].y + C1B * wy[k+3].y - C1A * wy[k+4].y) * INVH;
                float db1 = (C1A * wy[k].z - C1B * wy[k+1].z + C1B * wy[k+3].z - C1A * wy[k+4].z) * INVH;
                float ds1 = (C1A * wy[k].w - C1B * wy[k+1].w + C1B * wy[k+3].w - C1A * wy[k+4].w) * INVH;
                r.x = pav * po.x + pbv * db0;  r.y = pav * po.y + pbv * ds0;
                r.z = pav * po.z + pbv * db1;  r.w = pav * po.w + pbv * ds1;
            }
            pn[k] = r;
        }
        dpy_b0 = (C1A * pn[0].x - C1B * pn[1].x + C1B * pn[3].x - C1A * pn[4].x) * INVH;
        dpy_s0 = (C1A * pn[0].y - C1B * pn[1].y + C1B * pn[3].y - C1A * pn[4].y) * INVH;
        dpy_b1 = (C1A * pn[0].z - C1B * pn[1].z + C1B * pn[3].z - C1A * pn[4].z) * INVH;
        dpy_s1 = (C1A * pn[0].w - C1B * pn[1].w + C1B * pn[3].w - C1A * pn[4].w) * INVH;
        if (pby != 0.f)
            *(float4*)(g_py[nxt] + 2 * idx) = pn[2];
    } else {                                 // interior: 4 float4 row loads
        float4 m2 = *(const float4*)(wc + 2 * (idx - 2 * NP));
        float4 m1 = *(const float4*)(wc + 2 * (idx - NP));
        float4 p1 = *(const float4*)(wc + 2 * (idx + NP));
        float4 p2 = *(const float4*)(wc + 2 * (idx + 2 * NP));
        d2y_b0 = (C2A * (m2.x + p2.x) + C2B * (m1.x + p1.x) + C2C * w4.x) * INVH2;
        d2y_s0 = (C2A * (m2.y + p2.y) + C2B * (m1.y + p1.y) + C2C * w4.y) * INVH2;
        d2y_b1 = (C2A * (m2.z + p2.z) + C2B * (m1.z + p1.z) + C2C * w4.z) * INVH2;
        d2y_s1 = (C2A * (m2.w + p2.w) + C2B * (m1.w + p1.w) + C2C * w4.w) * INVH2;
    }

    // ---- zeta (in-place, own points) ----
    float zy_b0 = 0.f, zy_b1 = 0.f, zy_s0 = 0.f, zy_s1 = 0.f;
    float zx_b0 = 0.f, zx_b1 = 0.f, zx_s0 = 0.f, zx_s1 = 0.f;
    if (pby != 0.f) {
        float pay = g_pa[y];
        float4 zo = *(const float4*)(g_zy + 2 * idx);
        zy_b0 = pay * zo.x + pby * (d2y_b0 + dpy_b0);
        zy_s0 = pay * zo.y + pby * (d2y_s0 + dpy_s0);
        zy_b1 = pay * zo.z + pby * (d2y_b1 + dpy_b1);
        zy_s1 = pay * zo.w + pby * (d2y_s1 + dpy_s1);
        *(float4*)(g_zy + 2 * idx) = make_float4(zy_b0, zy_s0, zy_b1, zy_s1);
    }
    if (pbx0 != 0.f) {                       // pair-uniform
        float4 zo = *(const float4*)(g_zx + 2 * idx);
        zx_b0 = pax0 * zo.x + pbx0 * (d2x_b0 + dpx_b0);
        zx_s0 = pax0 * zo.y + pbx0 * (d2x_s0 + dpx_s0);
        zx_b1 = pax1 * zo.z + pbx1 * (d2x_b1 + dpx_b1);
        zx_s1 = pax1 * zo.w + pbx1 * (d2x_s1 + dpx_s1);
        *(float4*)(g_zx + 2 * idx) = make_float4(zx_b0, zx_s0, zx_b1, zx_s1);
    }

    // ---- lap + leapfrog + Born + source ----
    float4 vb   = *(const float4*)(g_vb + 2 * yx);        // (v0,bs0,v1,bs1)
    float4 prev = *(const float4*)(g_w[nxt] + 2 * idx);
    float lap_b0 = d2y_b0 + d2x_b0 + dpy_b0 + dpx_b0 + zy_b0 + zx_b0;
    float lap_s0 = d2y_s0 + d2x_s0 + dpy_s0 + dpx_s0 + zy_s0 + zx_s0;
    float lap_b1 = d2y_b1 + d2x_b1 + dpy_b1 + dpx_b1 + zy_b1 + zx_b1;
    float lap_s1 = d2y_s1 + d2x_s1 + dpy_s1 + dpx_s1 + zy_s1 + zx_s1;
    float wn_b0 = vb.x * lap_b0 + 2.f * w4.x - prev.x;
    float wn_s0 = vb.x * lap_s0 + 2.f * w4.y - prev.y + vb.y * lap_b0;
    float wn_b1 = vb.z * lap_b1 + 2.f * w4.z - prev.z;
    float wn_s1 = vb.z * lap_s1 + 2.f * w4.w - prev.w + vb.w * lap_b1;
    if (y == g_spos[2 * s]) {
        int sx = g_spos[2 * s + 1];
        if (sx == x0)      { wn_b0 += g_fbg[t * NS + s]; wn_s0 += g_fsc[t * NS + s]; }
        else if (sx == x1) { wn_b1 += g_fbg[t * NS + s]; wn_s1 += g_fsc[t * NS + s]; }
    }
    *(float4*)(g_w[nxt] + 2 * idx) = make_float4(wn_b0, wn_s0, wn_b1, wn_s1);
}

__global__ void finalize(const int* __restrict__ rloc, const int* __restrict__ rbloc,
                         void* __restrict__ out) {
    int i = blockIdx.x * blockDim.x + threadIdx.x;
    const float* w0 = g_w[0];     // NT even: newest field in buffer 0
    if (i < SNP2) {
        out_st(out, i,        w0[2 * i]);       // bg flat
        out_st(out, SNP2 + i, w0[2 * i + 1]);   // scattered flat
    }
    if (i < 2 * NS * NREC) {      // record last step (t = NT-1)
        bool isbg = i < NS * NREC;
        int k = isbg ? i : i - NS * NREC;
        int s = k / NREC, r = k % NREC;
        const int* rl = isbg ? rbloc : rloc;
        int ry = clampi(rl[(s * NREC + r) * 2 + 0], 0, NYX - 1) + PAD;
        int rx = clampi(rl[(s * NREC + r) * 2 + 1], 0, NYX - 1) + PAD;
        float val = w0[2 * (s * NP2 + ry * NP + rx) + (isbg ? 0 : 1)];
        int base = isbg ? (2 * SNP2) : (2 * SNP2 + NS * NREC * NT);
        out_st(out, base + (s * NREC + r) * NT + (NT - 1), val);
    }
}

extern "C" void kernel_launch(void* const* d_in, const int* in_sizes, int n_in,
                              void* d_out, int out_size, void* d_ws, size_t ws_size,
                              hipStream_t stream) {
    const void* v   = d_in[0];
    const void* sc  = d_in[1];
    const void* amp = d_in[2];
    const int* sloc  = (const int*)d_in[3];
    const int* rloc  = (const int*)d_in[4];
    const int* rbloc = (const int*)d_in[5];

    detect_mode<<<1, 64, 0, stream>>>(v);
    zero_state<<<(SNP2 / 2 + 255) / 256, 256, 0, stream>>>();
    prep_pad<<<(NP2 + 255) / 256, 256, 0, stream>>>(v, sc);
    prep_src<<<(NT * NS + 255) / 256, 256, 0, stream>>>(amp, sloc, v, sc);

    dim3 grid(1, NP, NS);
    for (int t = 0; t < NT; ++t)
        step_fused<<<grid, 256, 0, stream>>>(t, rloc, rbloc, d_out);

    finalize<<<(SNP2 + 255) / 256, 256, 0, stream>>>(rloc, rbloc, d_out);
}

// Round 14
// 3821.227 us; speedup vs baseline: 1.4107x; 1.1897x over previous
//
#include <hip/hip_runtime.h>
#include <hip/hip_bf16.h>

// ScalarBorn: 4th-order FD scalar wave + Born scattering with CPML, MI355X.
// R14 = exact revert to R11 (session best, 3829us): 1776 light blocks
// (row x shot), 256 thr x 2 pts, TWO barriers, w + psi_x_new staged in LDS,
// bg/scattered interleaved as (b,s) pairs -> float4 global accesses.
// Falsified alternatives: aggregation (R8/R10), barrier removal (R12/R13),
// load cuts (R7), cooperative grid.sync (R4).

constexpr int NYX  = 400;
constexpr int NS   = 4;
constexpr int NREC = 100;
constexpr int NT   = 300;
constexpr int PAD  = 22;
constexpr int NP   = 444;
constexpr int NP2  = NP * NP;          // 197136
constexpr int SNP2 = NS * NP2;         // 788544
constexpr float DT    = 0.0005f;
constexpr float INVH  = 0.2f;
constexpr float INVH2 = 0.04f;
constexpr float C1A = 1.0f / 12.0f;
constexpr float C1B = 2.0f / 3.0f;
constexpr float C2A = -1.0f / 12.0f;
constexpr float C2B = 4.0f / 3.0f;
constexpr float C2C = -2.5f;

// interleaved state: element (b,s) pair for grid index idx lives at [2*idx, 2*idx+1]
__device__ __align__(16) float g_w[2][2 * SNP2];   // wavefield ping-pong
__device__ __align__(16) float g_px[2][2 * SNP2];  // psi_x dbuf
__device__ __align__(16) float g_py[2][2 * SNP2];  // psi_y dbuf
__device__ __align__(16) float g_zx[2 * SNP2];     // zeta_x
__device__ __align__(16) float g_zy[2 * SNP2];     // zeta_y
__device__ __align__(16) float g_vb[2 * NP2];      // (v2dt2, bscale) pairs
__device__ float g_pa[NP];
__device__ float g_pb[NP];
__device__ float g_fbg[NT * NS];
__device__ float g_fsc[NT * NS];
__device__ int   g_spos[2 * NS];
__device__ int   g_mode;               // 1 = bf16 io, 0 = f32 io

__device__ __forceinline__ int clampi(int v, int lo, int hi) {
    return v < lo ? lo : (v > hi ? hi : v);
}
__device__ __forceinline__ float in_ld(const void* p, int i) {
    if (g_mode) return __bfloat162float(((const __hip_bfloat16*)p)[i]);
    return ((const float*)p)[i];
}
__device__ __forceinline__ void out_st(void* p, int i, float v) {
    if (g_mode) ((__hip_bfloat16*)p)[i] = __float2bfloat16(v);
    else        ((float*)p)[i] = v;
}
// float4 = (b0,s0,b1,s1) at row yy, col pair (2i,2i+1) of shot s; 0 if row OOB
__device__ __forceinline__ float4 ld4(const float* w, int s, int yy, int i) {
    if ((unsigned)yy >= (unsigned)NP) return make_float4(0.f, 0.f, 0.f, 0.f);
    return *(const float4*)(w + 2 * (s * NP2 + yy * NP + 2 * i));
}

__global__ void detect_mode(const void* vptr) {
    if (threadIdx.x == 0 && blockIdx.x == 0) {
        const __hip_bfloat16* p = (const __hip_bfloat16*)vptr;
        int ok = 1;
        for (int i = 0; i < 32; i += 2) {
            float f = __bfloat162float(p[i]);
            if (!(f >= 1000.f && f <= 3000.f)) ok = 0;
        }
        g_mode = ok;
    }
}

__global__ void zero_state() {
    int i = blockIdx.x * blockDim.x + threadIdx.x;
    if (i >= SNP2 / 2) return;           // each array = 2*SNP2 floats = SNP2/2 float4
    float4 z = make_float4(0.f, 0.f, 0.f, 0.f);
    ((float4*)g_w[0])[i] = z;  ((float4*)g_w[1])[i] = z;
    ((float4*)g_px[0])[i] = z; ((float4*)g_px[1])[i] = z;
    ((float4*)g_py[0])[i] = z; ((float4*)g_py[1])[i] = z;
    ((float4*)g_zx)[i] = z;    ((float4*)g_zy)[i] = z;
}

__global__ void prep_pad(const void* __restrict__ v, const void* __restrict__ sc) {
    int i = blockIdx.x * blockDim.x + threadIdx.x;
    if (i >= NP2) return;
    int y = i / NP, x = i % NP;
    int vy = clampi(y - PAD, 0, NYX - 1);
    int vx = clampi(x - PAD, 0, NYX - 1);
    float vv = in_ld(v, vy * NYX + vx);
    float vd = vv * DT;
    float s = 0.f;
    if (y >= PAD && y < PAD + NYX && x >= PAD && x < PAD + NYX)
        s = in_ld(sc, (y - PAD) * NYX + (x - PAD));
    g_vb[2 * i]     = vd * vd;
    g_vb[2 * i + 1] = 2.f * vv * s * DT * DT;
    if (i < NP) {
        float fi = (float)i;
        float f1 = fminf(fmaxf((22.f - fi) * 0.05f, 0.f), 1.f);
        float f2 = fminf(fmaxf((fi - 421.f) * 0.05f, 0.f), 1.f);
        float frac = fmaxf(f1, f2);
        float sigma = 259.0408229f * frac * frac;
        const float alpha = 78.53981634f;
        float a = expf(-(sigma + alpha) * DT);
        g_pa[i] = a;
        g_pb[i] = (sigma > 0.f) ? sigma / (sigma + alpha) * (a - 1.f) : 0.f;
    }
}

__global__ void prep_src(const void* __restrict__ amp, const int* __restrict__ sloc,
                         const void* __restrict__ v, const void* __restrict__ sc) {
    int i = blockIdx.x * blockDim.x + threadIdx.x;
    if (i >= NT * NS) return;
    int s = i % NS, t = i / NS;
    int ly = clampi(sloc[s * 2 + 0], 0, NYX - 1);
    int lx = clampi(sloc[s * 2 + 1], 0, NYX - 1);
    float a  = in_ld(amp, s * NT + t);
    float vv = in_ld(v,  ly * NYX + lx);
    float ss = in_ld(sc, ly * NYX + lx);
    g_fbg[i] = -a * vv * vv * DT * DT;
    g_fsc[i] = -2.f * a * vv * ss * DT * DT;
    if (i < NS) {
        g_spos[2 * i]     = ly + PAD;
        g_spos[2 * i + 1] = lx + PAD;
    }
}

// one fused timestep. Block = row y of shot s; 256 threads x 2 points.
// LDS layout: (b,s) pair of logical col c at float index 2*(c+2); pads zeroed.
__global__ void __launch_bounds__(256)
step_fused(int t, const int* __restrict__ rloc, const int* __restrict__ rbloc,
           void* __restrict__ out) {
    const int i = threadIdx.x;
    const int y = blockIdx.y;
    const int s = blockIdx.z;
    const int cur = t & 1, nxt = cur ^ 1;
    __shared__ __align__(16) float sw[904], spx[904];

    if (t > 0 && y == 0 && i < 2 * NREC) {    // record step t-1
        int r = i % NREC;
        bool isbg = i < NREC;
        const int* rl = isbg ? rbloc : rloc;
        int ry = clampi(rl[(s * NREC + r) * 2 + 0], 0, NYX - 1) + PAD;
        int rx = clampi(rl[(s * NREC + r) * 2 + 1], 0, NYX - 1) + PAD;
        float val = g_w[cur][2 * (s * NP2 + ry * NP + rx) + (isbg ? 0 : 1)];
        int base = isbg ? (2 * SNP2) : (2 * SNP2 + NS * NREC * NT);
        out_st(out, base + (s * NREC + r) * NT + (t - 1), val);
    }

    const bool active = i < 222;
    const int x0 = 2 * i, x1 = x0 + 1;
    const int yx  = y * NP + x0;
    const int idx = s * NP2 + yx;

    float4 w4 = make_float4(0.f, 0.f, 0.f, 0.f);   // (b0,s0,b1,s1)
    if (active) {
        w4 = *(const float4*)(g_w[cur] + 2 * idx);
        *(float4*)&sw[2 * x0 + 4] = w4;
    } else if (i == 222) {
        #pragma unroll
        for (int k = 0; k < 4; ++k) { sw[k] = 0.f; spx[k] = 0.f; }
    } else if (i == 223) {
        #pragma unroll
        for (int k = 892; k < 904; ++k) { sw[k] = 0.f; spx[k] = 0.f; }
    }
    __syncthreads();

    // ---- x stencils from LDS + own psi_x updates ----
    const bool pxreg = (i <= 11 || i >= 210);
    float pbx0 = 0.f, pbx1 = 0.f, pax0 = 0.f, pax1 = 0.f;
    float d2x_b0 = 0.f, d2x_b1 = 0.f, d2x_s0 = 0.f, d2x_s1 = 0.f;
    float4 pxn = make_float4(0.f, 0.f, 0.f, 0.f);
    float2 tm2, tm1, tp2, tp3;
    if (active) {
        tm2 = *(const float2*)&sw[2 * (x0 - 2) + 4];
        tm1 = *(const float2*)&sw[2 * (x0 - 1) + 4];
        tp2 = *(const float2*)&sw[2 * (x0 + 2) + 4];
        tp3 = *(const float2*)&sw[2 * (x0 + 3) + 4];
        d2x_b0 = (C2A * (tm2.x + tp2.x) + C2B * (tm1.x + w4.z) + C2C * w4.x) * INVH2;
        d2x_s0 = (C2A * (tm2.y + tp2.y) + C2B * (tm1.y + w4.w) + C2C * w4.y) * INVH2;
        d2x_b1 = (C2A * (tm1.x + tp3.x) + C2B * (w4.x + tp2.x) + C2C * w4.z) * INVH2;
        d2x_s1 = (C2A * (tm1.y + tp3.y) + C2B * (w4.y + tp2.y) + C2C * w4.w) * INVH2;
        pbx0 = g_pb[x0]; pbx1 = g_pb[x1];
        pax0 = g_pa[x0]; pax1 = g_pa[x1];
        if (pxreg && pbx0 != 0.f) {      // pb pair-uniform (frame edges even)
            float4 pxo = *(const float4*)(g_px[cur] + 2 * idx);
            float dwb0 = (C1A * tm2.x - C1B * tm1.x + C1B * w4.z - C1A * tp2.x) * INVH;
            float dws0 = (C1A * tm2.y - C1B * tm1.y + C1B * w4.w - C1A * tp2.y) * INVH;
            float dwb1 = (C1A * tm1.x - C1B * w4.x + C1B * tp2.x - C1A * tp3.x) * INVH;
            float dws1 = (C1A * tm1.y - C1B * w4.y + C1B * tp2.y - C1A * tp3.y) * INVH;
            pxn.x = pax0 * pxo.x + pbx0 * dwb0;
            pxn.y = pax0 * pxo.y + pbx0 * dws0;
            pxn.z = pax1 * pxo.z + pbx1 * dwb1;
            pxn.w = pax1 * pxo.w + pbx1 * dws1;
            *(float4*)(g_px[nxt] + 2 * idx) = pxn;
        }
        *(float4*)&spx[2 * x0 + 4] = pxn;
    }
    __syncthreads();
    if (!active) return;

    // ---- dpsi_x from LDS psi_x_new ----
    float dpx_b0 = 0.f, dpx_b1 = 0.f, dpx_s0 = 0.f, dpx_s1 = 0.f;
    if (pxreg) {
        float2 pm2 = *(const float2*)&spx[2 * (x0 - 2) + 4];
        float2 pm1 = *(const float2*)&spx[2 * (x0 - 1) + 4];
        float2 pp2 = *(const float2*)&spx[2 * (x0 + 2) + 4];
        float2 pp3 = *(const float2*)&spx[2 * (x0 + 3) + 4];
        dpx_b0 = (C1A * pm2.x - C1B * pm1.x + C1B * pxn.z - C1A * pp2.x) * INVH;
        dpx_s0 = (C1A * pm2.y - C1B * pm1.y + C1B * pxn.w - C1A * pp2.y) * INVH;
        dpx_b1 = (C1A * pm1.x - C1B * pxn.x + C1B * pp2.x - C1A * pp3.x) * INVH;
        dpx_s1 = (C1A * pm1.y - C1B * pxn.y + C1B * pp2.y - C1A * pp3.y) * INVH;
    }

    // ---- y direction ----
    const float pby = g_pb[y];               // block-uniform
    const bool yframe = (y <= 23 || y >= 420);
    float d2y_b0, d2y_b1, d2y_s0, d2y_s1;
    float dpy_b0 = 0.f, dpy_b1 = 0.f, dpy_s0 = 0.f, dpy_s1 = 0.f;
    if (yframe) {
        float4 wy[9];                        // rows y-4..y+4, (b0,s0,b1,s1)
        #pragma unroll
        for (int k = 0; k < 9; ++k)
            wy[k] = (k == 4) ? w4 : ld4(g_w[cur], s, y - 4 + k, i);
        d2y_b0 = (C2A * (wy[2].x + wy[6].x) + C2B * (wy[3].x + wy[5].x) + C2C * wy[4].x) * INVH2;
        d2y_s0 = (C2A * (wy[2].y + wy[6].y) + C2B * (wy[3].y + wy[5].y) + C2C * wy[4].y) * INVH2;
        d2y_b1 = (C2A * (wy[2].z + wy[6].z) + C2B * (wy[3].z + wy[5].z) + C2C * wy[4].z) * INVH2;
        d2y_s1 = (C2A * (wy[2].w + wy[6].w) + C2B * (wy[3].w + wy[5].w) + C2C * wy[4].w) * INVH2;
        float4 pn[5];                        // psi_y_new rows y-2..y+2
        #pragma unroll
        for (int k = 0; k < 5; ++k) {
            int yy = y - 2 + k;
            float pbv = ((unsigned)yy < (unsigned)NP) ? g_pb[yy] : 0.f;  // uniform
            float4 r = make_float4(0.f, 0.f, 0.f, 0.f);
            if (pbv != 0.f) {
                float pav = g_pa[yy];
                float4 po = *(const float4*)(g_py[cur] + 2 * (s * NP2 + yy * NP + x0));
                float db0 = (C1A * wy[k].x - C1B * wy[k+1].x + C1B * wy[k+3].x - C1A * wy[k+4].x) * INVH;
                float ds0 = (C1A * wy[k].y - C1B * wy[k+1].y + C1B * wy[k+3].y - C1A * wy[k+4].y) * INVH;
                float db1 = (C1A * wy[k].z - C1B * wy[k+1].z + C1B * wy[k+3].z - C1A * wy[k+4].z) * INVH;
                float ds1 = (C1A * wy[k].w - C1B * wy[k+1].w + C1B * wy[k+3].w - C1A * wy[k+4].w) * INVH;
                r.x = pav * po.x + pbv * db0;  r.y = pav * po.y + pbv * ds0;
                r.z = pav * po.z + pbv * db1;  r.w = pav * po.w + pbv * ds1;
            }
            pn[k] = r;
        }
        dpy_b0 = (C1A * pn[0].x - C1B * pn[1].x + C1B * pn[3].x - C1A * pn[4].x) * INVH;
        dpy_s0 = (C1A * pn[0].y - C1B * pn[1].y + C1B * pn[3].y - C1A * pn[4].y) * INVH;
        dpy_b1 = (C1A * pn[0].z - C1B * pn[1].z + C1B * pn[3].z - C1A * pn[4].z) * INVH;
        dpy_s1 = (C1A * pn[0].w - C1B * pn[1].w + C1B * pn[3].w - C1A * pn[4].w) * INVH;
        if (pby != 0.f)
            *(float4*)(g_py[nxt] + 2 * idx) = pn[2];
    } else {                                 // interior: 4 float4 row loads
        float4 m2 = *(const float4*)(g_w[cur] + 2 * (idx - 2 * NP));
        float4 m1 = *(const float4*)(g_w[cur] + 2 * (idx - NP));
        float4 p1 = *(const float4*)(g_w[cur] + 2 * (idx + NP));
        float4 p2 = *(const float4*)(g_w[cur] + 2 * (idx + 2 * NP));
        d2y_b0 = (C2A * (m2.x + p2.x) + C2B * (m1.x + p1.x) + C2C * w4.x) * INVH2;
        d2y_s0 = (C2A * (m2.y + p2.y) + C2B * (m1.y + p1.y) + C2C * w4.y) * INVH2;
        d2y_b1 = (C2A * (m2.z + p2.z) + C2B * (m1.z + p1.z) + C2C * w4.z) * INVH2;
        d2y_s1 = (C2A * (m2.w + p2.w) + C2B * (m1.w + p1.w) + C2C * w4.w) * INVH2;
    }

    // ---- zeta (in-place, own points, paired float4) ----
    float zy_b0 = 0.f, zy_b1 = 0.f, zy_s0 = 0.f, zy_s1 = 0.f;
    float zx_b0 = 0.f, zx_b1 = 0.f, zx_s0 = 0.f, zx_s1 = 0.f;
    if (pby != 0.f) {
        float pay = g_pa[y];
        float4 zo = *(const float4*)(g_zy + 2 * idx);
        zy_b0 = pay * zo.x + pby * (d2y_b0 + dpy_b0);
        zy_s0 = pay * zo.y + pby * (d2y_s0 + dpy_s0);
        zy_b1 = pay * zo.z + pby * (d2y_b1 + dpy_b1);
        zy_s1 = pay * zo.w + pby * (d2y_s1 + dpy_s1);
        *(float4*)(g_zy + 2 * idx) = make_float4(zy_b0, zy_s0, zy_b1, zy_s1);
    }
    if (pbx0 != 0.f) {                       // pair-uniform
        float4 zo = *(const float4*)(g_zx + 2 * idx);
        zx_b0 = pax0 * zo.x + pbx0 * (d2x_b0 + dpx_b0);
        zx_s0 = pax0 * zo.y + pbx0 * (d2x_s0 + dpx_s0);
        zx_b1 = pax1 * zo.z + pbx1 * (d2x_b1 + dpx_b1);
        zx_s1 = pax1 * zo.w + pbx1 * (d2x_s1 + dpx_s1);
        *(float4*)(g_zx + 2 * idx) = make_float4(zx_b0, zx_s0, zx_b1, zx_s1);
    }

    // ---- lap + leapfrog + Born + source ----
    float4 vb   = *(const float4*)(g_vb + 2 * yx);        // (v0,bs0,v1,bs1)
    float4 prev = *(const float4*)(g_w[nxt] + 2 * idx);
    float lap_b0 = d2y_b0 + d2x_b0 + dpy_b0 + dpx_b0 + zy_b0 + zx_b0;
    float lap_s0 = d2y_s0 + d2x_s0 + dpy_s0 + dpx_s0 + zy_s0 + zx_s0;
    float lap_b1 = d2y_b1 + d2x_b1 + dpy_b1 + dpx_b1 + zy_b1 + zx_b1;
    float lap_s1 = d2y_s1 + d2x_s1 + dpy_s1 + dpx_s1 + zy_s1 + zx_s1;
    float wn_b0 = vb.x * lap_b0 + 2.f * w4.x - prev.x;
    float wn_s0 = vb.x * lap_s0 + 2.f * w4.y - prev.y + vb.y * lap_b0;
    float wn_b1 = vb.z * lap_b1 + 2.f * w4.z - prev.z;
    float wn_s1 = vb.z * lap_s1 + 2.f * w4.w - prev.w + vb.w * lap_b1;
    if (y == g_spos[2 * s]) {
        int sx = g_spos[2 * s + 1];
        if (sx == x0)      { wn_b0 += g_fbg[t * NS + s]; wn_s0 += g_fsc[t * NS + s]; }
        else if (sx == x1) { wn_b1 += g_fbg[t * NS + s]; wn_s1 += g_fsc[t * NS + s]; }
    }
    *(float4*)(g_w[nxt] + 2 * idx) = make_float4(wn_b0, wn_s0, wn_b1, wn_s1);
}

__global__ void finalize(const int* __restrict__ rloc, const int* __restrict__ rbloc,
                         void* __restrict__ out) {
    int i = blockIdx.x * blockDim.x + threadIdx.x;
    const float* w0 = g_w[0];     // NT even: newest field in buffer 0
    if (i < SNP2) {
        out_st(out, i,        w0[2 * i]);       // bg flat
        out_st(out, SNP2 + i, w0[2 * i + 1]);   // scattered flat
    }
    if (i < 2 * NS * NREC) {      // record last step (t = NT-1)
        bool isbg = i < NS * NREC;
        int k = isbg ? i : i - NS * NREC;
        int s = k / NREC, r = k % NREC;
        const int* rl = isbg ? rbloc : rloc;
        int ry = clampi(rl[(s * NREC + r) * 2 + 0], 0, NYX - 1) + PAD;
        int rx = clampi(rl[(s * NREC + r) * 2 + 1], 0, NYX - 1) + PAD;
        float val = w0[2 * (s * NP2 + ry * NP + rx) + (isbg ? 0 : 1)];
        int base = isbg ? (2 * SNP2) : (2 * SNP2 + NS * NREC * NT);
        out_st(out, base + (s * NREC + r) * NT + (NT - 1), val);
    }
}

extern "C" void kernel_launch(void* const* d_in, const int* in_sizes, int n_in,
                              void* d_out, int out_size, void* d_ws, size_t ws_size,
                              hipStream_t stream) {
    const void* v   = d_in[0];
    const void* sc  = d_in[1];
    const void* amp = d_in[2];
    const int* sloc  = (const int*)d_in[3];
    const int* rloc  = (const int*)d_in[4];
    const int* rbloc = (const int*)d_in[5];

    detect_mode<<<1, 64, 0, stream>>>(v);
    zero_state<<<(SNP2 / 2 + 255) / 256, 256, 0, stream>>>();
    prep_pad<<<(NP2 + 255) / 256, 256, 0, stream>>>(v, sc);
    prep_src<<<(NT * NS + 255) / 256, 256, 0, stream>>>(amp, sloc, v, sc);

    dim3 grid(1, NP, NS);
    for (int t = 0; t < NT; ++t)
        step_fused<<<grid, 256, 0, stream>>>(t, rloc, rbloc, d_out);

    finalize<<<(SNP2 + 255) / 256, 256, 0, stream>>>(rloc, rbloc, d_out);
}